// Round 12
// baseline (156.782 us; speedup 1.0000x reference)
//
#include <hip/hip_runtime.h>
#include <stdint.h>

#define BATCH 4
#define NPTS 4096
#define KNN 11            // K+1 neighbors including self
#define LPQ 32            // lanes per query (r12: was 16 -> 2x waves)
#define QPB 8             // queries per block (256 threads / 32 lanes)
#define CHUNK 512         // LDS candidate chunk (8.7 KB skewed)
#define NCHUNK (NPTS / CHUNK)     // 8
#define CPL (CHUNK / LPQ)         // 16 candidates per lane per chunk
#define BUFN 8            // per-lane qualifier buffer slots (16 KB)
#define SENT_BITS 0x433FFFFFFFFFFFFFll

// monotone float -> uint mapping (ascending)
__device__ __forceinline__ unsigned sortable_f32(float d) {
    unsigned b = __float_as_uint(d);
    unsigned m = (unsigned)(((int)b) >> 31) | 0x80000000u;
    return b ^ m;
}

// Fused exact 11-NN + MLP. FROZEN d2 arithmetic (verified r4-r11):
//   sq_j = fl(fl(x2)+fl(y2)) + fl(z2); dot = fma chain; d2 = fl(si+sj)-fl(2t).
// top-k ascending d2, ties -> lower index; key = double with bits
// 0x433<<52 | sortable(d2)<<12 | j  (f64 order == (d2 asc, j asc)).
// r12: 32 lanes/query (6 waves/SIMD, was grid-capped at 4); exact tau
// pop-merge only on the first 3 flushes then frozen (frozen tau >= running
// 11th >= final 11th -> gate stays conservative -> result exact).
__global__ __launch_bounds__(256, 6) void fused_kernel(
    const float* __restrict__ pos, const float* __restrict__ vel,
    const float* __restrict__ initc,
    const float* __restrict__ W1, const float* __restrict__ b1,
    const float* __restrict__ W2, const float* __restrict__ b2,
    const float* __restrict__ W3, const float* __restrict__ b3,
    float* __restrict__ out)
{
#pragma clang fp contract(off)
    // skewed float4 (x,y,z,sq): idx + (idx>>4) -> partitions offset 16B
    __shared__ float4 sp[CHUNK + LPQ];
    // slot-major lane-private buffers: lanes 8B apart -> 2-way -> free
    __shared__ unsigned long long buf[BUFN * 256];

    int b    = blockIdx.x >> 9;           // 512 blocks per batch
    int qblk = blockIdx.x & 511;
    int tid  = threadIdx.x;
    const float* pb = pos + (size_t)b * NPTS * 3;

    int q = tid >> 5, p = tid & 31;
    int i = qblk * QPB + q;               // query index within batch

    float xq = pb[3*i], yq = pb[3*i+1], zq = pb[3*i+2];
    float sqq = xq*xq + yq*yq + zq*zq;    // contract(off): np sum order

    double kd[KNN];
#pragma unroll
    for (int k = 0; k < KNN; ++k) kd[k] = __longlong_as_double(SENT_BITS);
    float tau_f = __builtin_inff();       // stale-conservative gate threshold
    int cnt = 0, nflush = 0;

    for (int c = 0; c < NCHUNK; ++c) {
        if (c) __syncthreads();
        for (int j = tid; j < CHUNK; j += 256) {
            int g = c * CHUNK + j;
            float x = pb[3*g], y = pb[3*g+1], z = pb[3*g+2];
            float sq = x*x + y*y + z*z;   // FROZEN staged sq
            sp[j + (j >> 4)] = make_float4(x, y, z, sq);
        }
        __syncthreads();

        int sbase = p * (CPL + 1);
        int jg    = c * CHUNK + p * CPL;
        for (int jl = 0; jl < CPL; jl += 4) {
            // 4 back-to-back LDS reads + 4 independent d2 chains
            float4 c0 = sp[sbase + jl + 0];
            float4 c1 = sp[sbase + jl + 1];
            float4 c2 = sp[sbase + jl + 2];
            float4 c3 = sp[sbase + jl + 3];
            float t0 = xq*c0.x, t1 = xq*c1.x, t2 = xq*c2.x, t3 = xq*c3.x;
            t0 = fmaf(yq, c0.y, t0); t1 = fmaf(yq, c1.y, t1);
            t2 = fmaf(yq, c2.y, t2); t3 = fmaf(yq, c3.y, t3);
            t0 = fmaf(zq, c0.z, t0); t1 = fmaf(zq, c1.z, t1);
            t2 = fmaf(zq, c2.z, t2); t3 = fmaf(zq, c3.z, t3);
            float d0 = (sqq + c0.w) - 2.0f*t0;
            float d1 = (sqq + c1.w) - 2.0f*t1;
            float d2 = (sqq + c2.w) - 2.0f*t2;
            float d3 = (sqq + c3.w) - 2.0f*t3;

            // f32 gate (== u32 gate by monotonicity); pack only on accept
#pragma unroll
            for (int s = 0; s < 4; ++s) {
                float dv = s == 0 ? d0 : s == 1 ? d1 : s == 2 ? d2 : d3;
                if (dv <= tau_f) {
                    unsigned u  = sortable_f32(dv);
                    unsigned lo = (u << 12) | (unsigned)(jg + jl + s);
                    unsigned hi = 0x43300000u | (u >> 20);
                    buf[cnt * 256 + tid] =
                        ((unsigned long long)hi << 32) | (unsigned long long)lo;
                    ++cnt;
                }
            }

            if (__any(cnt > BUFN - 4)) {
                // ---- flush: drain buffers through the f64 network ----
                for (int k = 0; k < BUFN; ++k) {
                    if (!__any(cnt > k)) break;
                    unsigned long long kb = buf[k * 256 + tid];
                    double key = (k < cnt) ? __longlong_as_double(kb)
                                           : __longlong_as_double(SENT_BITS);
#pragma unroll
                    for (int kk = KNN-1; kk > 0; --kk) {
                        double mn = fmin(kd[kk], key);
                        kd[kk] = fmax(kd[kk-1], mn);
                    }
                    kd[0] = fmin(kd[0], key);
                }
                cnt = 0;
                if (nflush < 3) {         // exact tau only while it matters
                    ++nflush;
                    double tmp[KNN];
#pragma unroll
                    for (int k = 0; k < KNN; ++k) tmp[k] = kd[k];
                    double h = tmp[0];
#pragma unroll
                    for (int r = 0; r < KNN; ++r) {
                        h = tmp[0];
#pragma unroll
                        for (int m = 1; m <= 16; m <<= 1)
                            h = fmin(h, __shfl_xor(h, m, LPQ));
                        bool own = (__double_as_longlong(tmp[0]) ==
                                    __double_as_longlong(h));
#pragma unroll
                        for (int t2 = 0; t2 < KNN-1; ++t2)
                            tmp[t2] = own ? tmp[t2+1] : tmp[t2];
                        tmp[KNN-1] = own ? __longlong_as_double(SENT_BITS)
                                         : tmp[KNN-1];
                    }
                    unsigned tau_u = (unsigned)((unsigned long long)
                                                __double_as_longlong(h) >> 12);
                    tau_f = __uint_as_float(tau_u ^ 0x80000000u);
                }
            }
        }
    }

    // final drain
    for (int k = 0; k < BUFN; ++k) {
        if (!__any(cnt > k)) break;
        unsigned long long kb = buf[k * 256 + tid];
        double key = (k < cnt) ? __longlong_as_double(kb)
                               : __longlong_as_double(SENT_BITS);
#pragma unroll
        for (int kk = KNN-1; kk > 0; --kk) {
            double mn = fmin(kd[kk], key);
            kd[kk] = fmax(kd[kk-1], mn);
        }
        kd[0] = fmin(kd[0], key);
    }

    // destructive 32-lane merge -> res[] = original indices (all lanes)
    unsigned res[KNN];
#pragma unroll
    for (int r = 0; r < KNN; ++r) {
        double h = kd[0];
#pragma unroll
        for (int m = 1; m <= 16; m <<= 1)
            h = fmin(h, __shfl_xor(h, m, LPQ));
        long long hb = __double_as_longlong(h);
        res[r] = (unsigned)(hb & 0xFFF);
        bool own = (__double_as_longlong(kd[0]) == hb);
#pragma unroll
        for (int t = 0; t < KNN-1; ++t) kd[t] = own ? kd[t+1] : kd[t];
        kd[KNN-1] = own ? __longlong_as_double(SENT_BITS) : kd[KNN-1];
    }

    // ---------- fused MLP, lane-parallel, BIT-IDENTICAL to r8 ----------
    // all 32 lanes compute with pm = p&15 (second half redundant -> no
    // divergence); lanes p<6 store.
    const float* vb = vel + (size_t)b * NPTS * 3;
    int pm = p & 15;

    const float* w0 = W1 + (2*pm)   * 66;
    const float* w1 = W1 + (2*pm+1) * 66;
    float a0 = b1[2*pm], a1 = b1[2*pm+1];
#pragma unroll
    for (int k = 1; k < KNN; ++k) {       // ff 0..29: relative positions
        const float* pn = pb + 3*(int)res[k];
        float dx = pn[0] - xq, dy = pn[1] - yq, dz = pn[2] - zq;
        int ff = 3*(k-1);
        a0 = fmaf(dx, w0[ff+0], a0); a1 = fmaf(dx, w1[ff+0], a1);
        a0 = fmaf(dy, w0[ff+1], a0); a1 = fmaf(dy, w1[ff+1], a1);
        a0 = fmaf(dz, w0[ff+2], a0); a1 = fmaf(dz, w1[ff+2], a1);
    }
#pragma unroll
    for (int k = 0; k < KNN; ++k) {       // ff 30..62: velocities
        const float* vn = vb + 3*(int)res[k];
        int ff = 30 + 3*k;
        a0 = fmaf(vn[0], w0[ff+0], a0); a1 = fmaf(vn[0], w1[ff+0], a1);
        a0 = fmaf(vn[1], w0[ff+1], a0); a1 = fmaf(vn[1], w1[ff+1], a1);
        a0 = fmaf(vn[2], w0[ff+2], a0); a1 = fmaf(vn[2], w1[ff+2], a1);
    }
    float c0i = initc[b*3+0], c1i = initc[b*3+1], c2i = initc[b*3+2];
    a0 = fmaf(c0i, w0[63], a0); a1 = fmaf(c0i, w1[63], a1);
    a0 = fmaf(c1i, w0[64], a0); a1 = fmaf(c1i, w1[64], a1);
    a0 = fmaf(c2i, w0[65], a0); a1 = fmaf(c2i, w1[65], a1);

    // h1[ii] (ii=0..31) lives on lanes 0..15 of the segment (2 rows/lane)
    float h2 = b2[pm];
    const float* w2 = W2 + pm * 32;
#pragma unroll
    for (int ii = 0; ii < 32; ++ii) {
        float h1v = __shfl((ii & 1) ? a1 : a0, ii >> 1, LPQ);
        h2 = fmaf(h1v, w2[ii], h2);
    }
    int o3 = pm < 6 ? pm : 0;
    float po = b3[o3];
    const float* w3 = W3 + o3 * 16;
#pragma unroll
    for (int ii = 0; ii < 16; ++ii) {
        float h2v = __shfl(h2, ii, LPQ);  // rows 0..15 on lanes 0..15
        po = fmaf(h2v, w3[ii], po);
    }
    float resid = (p == 0) ? xq : (p == 1) ? yq : (p == 2) ? zq : 0.0f;
    po += resid;                           // residual on first 3 channels

    if (p < 6)
        out[((size_t)b * NPTS + (size_t)i) * 6 + p] = po;
}

extern "C" void kernel_launch(void* const* d_in, const int* in_sizes, int n_in,
                              void* d_out, int out_size, void* d_ws, size_t ws_size,
                              hipStream_t stream) {
    const float* pos   = (const float*)d_in[0];
    const float* vel   = (const float*)d_in[1];
    const float* initc = (const float*)d_in[2];
    const float* W1    = (const float*)d_in[3];
    const float* b1    = (const float*)d_in[4];
    const float* W2    = (const float*)d_in[5];
    const float* b2    = (const float*)d_in[6];
    const float* W3    = (const float*)d_in[7];
    const float* b3    = (const float*)d_in[8];
    float* out = (float*)d_out;

    fused_kernel<<<dim3(BATCH * (NPTS / QPB)), dim3(256), 0, stream>>>(
        pos, vel, initc, W1, b1, W2, b2, W3, b3, out);
}

// Round 13
// 124.195 us; speedup vs baseline: 1.2624x; 1.2624x over previous
//
#include <hip/hip_runtime.h>
#include <stdint.h>

#define BATCH 4
#define NPTS 4096
#define KNN 11            // K+1 neighbors including self
#define LPQ 16            // lanes per query
#define QPB 16            // queries per block
#define CHUNK 1024        // LDS candidate chunk
#define NCHUNK (NPTS / CHUNK)     // 4
#define CPL (CHUNK / LPQ)         // 64 candidates per lane per chunk
#define BUFN 10           // per-lane qualifier buffer slots
#define SENT_BITS 0x433FFFFFFFFFFFFFll

// monotone float -> uint mapping (ascending)
__device__ __forceinline__ unsigned sortable_f32(float d) {
    unsigned b = __float_as_uint(d);
    unsigned m = (unsigned)(((int)b) >> 31) | 0x80000000u;
    return b ^ m;
}

// Fused exact 11-NN + MLP. FROZEN d2 arithmetic (verified r4-r12):
//   sq_j = fl(fl(x2)+fl(y2)) + fl(z2); dot = fma chain; d2 = fl(si+sj)-fl(2t).
// top-k ascending d2, ties -> lower index; key = double with bits
// 0x433<<52 | sortable(d2)<<12 | j  (f64 order == (d2 asc, j asc)).
// r13 = r11 verbatim + ONE change: the exact tau pop-merge (55 dependent
// shfls, the largest non-scan cost) runs only on the first 3 flushes, then
// tau freezes. Frozen tau = exact running 11th at freeze >= final 11th ->
// gate stays conservative -> result exact; drains still run every flush.
__global__ __launch_bounds__(256, 4) void fused_kernel(
    const float* __restrict__ pos, const float* __restrict__ vel,
    const float* __restrict__ initc,
    const float* __restrict__ W1, const float* __restrict__ b1,
    const float* __restrict__ W2, const float* __restrict__ b2,
    const float* __restrict__ W3, const float* __restrict__ b3,
    float* __restrict__ out)
{
#pragma clang fp contract(off)
    // skewed float4 (x,y,z,sq): idx + (idx>>6) -> partitions offset by 16B
    __shared__ float4 sp[CHUNK + LPQ];
    // slot-major lane-private buffers: lanes 8B apart -> 2-way -> free
    __shared__ unsigned long long buf[BUFN * 256];

    int b    = blockIdx.x >> 8;           // 256 blocks per batch
    int qblk = blockIdx.x & 255;
    int tid  = threadIdx.x;
    const float* pb = pos + (size_t)b * NPTS * 3;

    int q = tid >> 4, p = tid & 15;
    int i = qblk * QPB + q;               // query index within batch

    float xq = pb[3*i], yq = pb[3*i+1], zq = pb[3*i+2];
    float sqq = xq*xq + yq*yq + zq*zq;    // contract(off): np sum order

    double kd[KNN];
#pragma unroll
    for (int k = 0; k < KNN; ++k) kd[k] = __longlong_as_double(SENT_BITS);
    float tau_f = __builtin_inff();       // stale-conservative gate threshold
    int cnt = 0, nflush = 0;

    for (int c = 0; c < NCHUNK; ++c) {
        if (c) __syncthreads();
        for (int j = tid; j < CHUNK; j += 256) {
            int g = c * CHUNK + j;
            float x = pb[3*g], y = pb[3*g+1], z = pb[3*g+2];
            float sq = x*x + y*y + z*z;   // FROZEN staged sq
            sp[j + (j >> 6)] = make_float4(x, y, z, sq);
        }
        __syncthreads();

        int sbase = p * (CPL + 1);
        int jg    = c * CHUNK + p * CPL;
        for (int jl = 0; jl < CPL; jl += 4) {
            // 4 back-to-back LDS reads + 4 independent d2 chains (ILP)
            float4 c0 = sp[sbase + jl + 0];
            float4 c1 = sp[sbase + jl + 1];
            float4 c2 = sp[sbase + jl + 2];
            float4 c3 = sp[sbase + jl + 3];
            float t0 = xq*c0.x, t1 = xq*c1.x, t2 = xq*c2.x, t3 = xq*c3.x;
            t0 = fmaf(yq, c0.y, t0); t1 = fmaf(yq, c1.y, t1);
            t2 = fmaf(yq, c2.y, t2); t3 = fmaf(yq, c3.y, t3);
            t0 = fmaf(zq, c0.z, t0); t1 = fmaf(zq, c1.z, t1);
            t2 = fmaf(zq, c2.z, t2); t3 = fmaf(zq, c3.z, t3);
            float d0 = (sqq + c0.w) - 2.0f*t0;
            float d1 = (sqq + c1.w) - 2.0f*t1;
            float d2 = (sqq + c2.w) - 2.0f*t2;
            float d3 = (sqq + c3.w) - 2.0f*t3;

            // f32 gate (== u32 gate by monotonicity); pack only on accept
#pragma unroll
            for (int s = 0; s < 4; ++s) {
                float dv = s == 0 ? d0 : s == 1 ? d1 : s == 2 ? d2 : d3;
                if (dv <= tau_f) {
                    unsigned u  = sortable_f32(dv);
                    unsigned lo = (u << 12) | (unsigned)(jg + jl + s);
                    unsigned hi = 0x43300000u | (u >> 20);
                    buf[cnt * 256 + tid] =
                        ((unsigned long long)hi << 32) | (unsigned long long)lo;
                    ++cnt;
                }
            }

            if (__any(cnt > BUFN - 4)) {
                // ---- flush: drain buffers through the f64 network ----
                for (int k = 0; k < BUFN; ++k) {
                    if (!__any(cnt > k)) break;     // early out (late flushes)
                    unsigned long long kb = buf[k * 256 + tid];
                    double key = (k < cnt) ? __longlong_as_double(kb)
                                           : __longlong_as_double(SENT_BITS);
#pragma unroll
                    for (int kk = KNN-1; kk > 0; --kk) {
                        double mn = fmin(kd[kk], key);
                        kd[kk] = fmax(kd[kk-1], mn);
                    }
                    kd[0] = fmin(kd[0], key);
                }
                cnt = 0;
                if (nflush < 3) {         // exact tau only while it matters
                    ++nflush;
                    double tmp[KNN];
#pragma unroll
                    for (int k = 0; k < KNN; ++k) tmp[k] = kd[k];
                    double h = tmp[0];
#pragma unroll
                    for (int r = 0; r < KNN; ++r) {
                        h = tmp[0];
#pragma unroll
                        for (int m = 1; m <= 8; m <<= 1)
                            h = fmin(h, __shfl_xor(h, m, LPQ));
                        bool own = (__double_as_longlong(tmp[0]) ==
                                    __double_as_longlong(h));
#pragma unroll
                        for (int t2 = 0; t2 < KNN-1; ++t2)
                            tmp[t2] = own ? tmp[t2+1] : tmp[t2];
                        tmp[KNN-1] = own ? __longlong_as_double(SENT_BITS)
                                         : tmp[KNN-1];
                    }
                    unsigned tau_u = (unsigned)((unsigned long long)
                                                __double_as_longlong(h) >> 12);
                    // unsortable: real d2 keys have top bit set
                    tau_f = __uint_as_float(tau_u ^ 0x80000000u);
                }
            }
        }
    }

    // final drain
    for (int k = 0; k < BUFN; ++k) {
        if (!__any(cnt > k)) break;
        unsigned long long kb = buf[k * 256 + tid];
        double key = (k < cnt) ? __longlong_as_double(kb)
                               : __longlong_as_double(SENT_BITS);
#pragma unroll
        for (int kk = KNN-1; kk > 0; --kk) {
            double mn = fmin(kd[kk], key);
            kd[kk] = fmax(kd[kk-1], mn);
        }
        kd[0] = fmin(kd[0], key);
    }

    // destructive 16-lane merge (r8 verbatim) -> res[] = original indices
    unsigned res[KNN];
#pragma unroll
    for (int r = 0; r < KNN; ++r) {
        double h = kd[0];
#pragma unroll
        for (int m = 1; m <= 8; m <<= 1)
            h = fmin(h, __shfl_xor(h, m, LPQ));
        long long hb = __double_as_longlong(h);
        res[r] = (unsigned)(hb & 0xFFF);
        bool own = (__double_as_longlong(kd[0]) == hb);
#pragma unroll
        for (int t = 0; t < KNN-1; ++t) kd[t] = own ? kd[t+1] : kd[t];
        kd[KNN-1] = own ? __longlong_as_double(SENT_BITS) : kd[KNN-1];
    }

    // ---------- fused MLP, lane-parallel, BIT-IDENTICAL to r8 ----------
    const float* vb = vel + (size_t)b * NPTS * 3;

    const float* w0 = W1 + (2*p)   * 66;
    const float* w1 = W1 + (2*p+1) * 66;
    float a0 = b1[2*p], a1 = b1[2*p+1];
#pragma unroll
    for (int k = 1; k < KNN; ++k) {       // ff 0..29: relative positions
        const float* pn = pb + 3*(int)res[k];
        float dx = pn[0] - xq, dy = pn[1] - yq, dz = pn[2] - zq;
        int ff = 3*(k-1);
        a0 = fmaf(dx, w0[ff+0], a0); a1 = fmaf(dx, w1[ff+0], a1);
        a0 = fmaf(dy, w0[ff+1], a0); a1 = fmaf(dy, w1[ff+1], a1);
        a0 = fmaf(dz, w0[ff+2], a0); a1 = fmaf(dz, w1[ff+2], a1);
    }
#pragma unroll
    for (int k = 0; k < KNN; ++k) {       // ff 30..62: velocities
        const float* vn = vb + 3*(int)res[k];
        int ff = 30 + 3*k;
        a0 = fmaf(vn[0], w0[ff+0], a0); a1 = fmaf(vn[0], w1[ff+0], a1);
        a0 = fmaf(vn[1], w0[ff+1], a0); a1 = fmaf(vn[1], w1[ff+1], a1);
        a0 = fmaf(vn[2], w0[ff+2], a0); a1 = fmaf(vn[2], w1[ff+2], a1);
    }
    float c0i = initc[b*3+0], c1i = initc[b*3+1], c2i = initc[b*3+2];
    a0 = fmaf(c0i, w0[63], a0); a1 = fmaf(c0i, w1[63], a1);
    a0 = fmaf(c1i, w0[64], a0); a1 = fmaf(c1i, w1[64], a1);
    a0 = fmaf(c2i, w0[65], a0); a1 = fmaf(c2i, w1[65], a1);

    float h2 = b2[p];
    const float* w2 = W2 + p * 32;
#pragma unroll
    for (int ii = 0; ii < 32; ++ii) {
        float h1v = __shfl((ii & 1) ? a1 : a0, ii >> 1, LPQ);
        h2 = fmaf(h1v, w2[ii], h2);
    }
    int o3 = p < 6 ? p : 0;
    float po = b3[o3];
    const float* w3 = W3 + o3 * 16;
#pragma unroll
    for (int ii = 0; ii < 16; ++ii) {
        float h2v = __shfl(h2, ii, LPQ);
        po = fmaf(h2v, w3[ii], po);
    }
    float resid = (p == 0) ? xq : (p == 1) ? yq : (p == 2) ? zq : 0.0f;
    po += resid;                           // residual on first 3 channels

    if (p < 6)
        out[((size_t)b * NPTS + (size_t)i) * 6 + p] = po;
}

extern "C" void kernel_launch(void* const* d_in, const int* in_sizes, int n_in,
                              void* d_out, int out_size, void* d_ws, size_t ws_size,
                              hipStream_t stream) {
    const float* pos   = (const float*)d_in[0];
    const float* vel   = (const float*)d_in[1];
    const float* initc = (const float*)d_in[2];
    const float* W1    = (const float*)d_in[3];
    const float* b1    = (const float*)d_in[4];
    const float* W2    = (const float*)d_in[5];
    const float* b2    = (const float*)d_in[6];
    const float* W3    = (const float*)d_in[7];
    const float* b3    = (const float*)d_in[8];
    float* out = (float*)d_out;

    fused_kernel<<<dim3(BATCH * (NPTS / QPB)), dim3(256), 0, stream>>>(
        pos, vel, initc, W1, b1, W2, b2, W3, b3, out);
}